// Round 1
// baseline (673.138 us; speedup 1.0000x reference)
//
#include <hip/hip_runtime.h>
#include <hip/hip_bf16.h>
#include <cstdint>

#define B_ 8
#define T_ 2048
#define E_ 256
#define K_ 512
#define KS_ 9
#define L_ 8192
#define PAD_ 4
#define TP_ (T_ + 2 * PAD_)   // 2056
#define KK_ (E_ * KS_)        // 2304

typedef __bf16 bf16x8 __attribute__((ext_vector_type(8)));
typedef float f32x4 __attribute__((ext_vector_type(4)));

__device__ __forceinline__ unsigned short f2bf(float f) {
  union { float f; unsigned int u; } a; a.f = f;
  unsigned int r = (a.u + 0x7FFFu + ((a.u >> 16) & 1u)) >> 16;
  return (unsigned short)r;
}

__device__ __forceinline__ void gld_lds16(const void* g, void* l) {
  // async global->LDS, 16B per lane; LDS dest = wave-uniform base + lane*16
  __builtin_amdgcn_global_load_lds(
      (const __attribute__((address_space(1))) unsigned int*)g,
      (__attribute__((address_space(3))) unsigned int*)l, 16, 0, 0);
}

__device__ __forceinline__ f32x4 mfma_bf16(bf16x8 a, bf16x8 b, f32x4 c) {
  return __builtin_amdgcn_mfma_f32_16x16x32_bf16(a, b, c, 0, 0, 0);
}

// swizzled chunk offset (in shorts) for frag reads: 2-way conflict-free
__device__ __forceinline__ int frag_off(int r, int q) {
  return (4 * r + ((q + (r >> 1)) & 3)) * 8;
}

// ---------------- prep: embed gather + zero halo, cast to bf16 ----------------
__global__ __launch_bounds__(256) void k_embed(const int* __restrict__ ids,
                                               const float* __restrict__ emb,
                                               unsigned short* __restrict__ xpad) {
  int gid = blockIdx.x * 256 + threadIdx.x;
  int row = gid >> 6;              // 0 .. B_*TP_-1
  int e4 = (gid & 63) << 2;
  int b = row / TP_;
  int tp = row - b * TP_;
  float4 v = make_float4(0.f, 0.f, 0.f, 0.f);
  if (tp >= PAD_ && tp < T_ + PAD_) {
    int id = ids[b * T_ + tp - PAD_];
    v = *(const float4*)(emb + (size_t)id * E_ + e4);
  }
  ushort4 o;
  o.x = f2bf(v.x); o.y = f2bf(v.y); o.z = f2bf(v.z); o.w = f2bf(v.w);
  *(ushort4*)(xpad + (size_t)row * E_ + e4) = o;
}

// ---------------- prep: conv_w [K,E,KS] -> W_t [K][j*256+e] bf16 ----------------
__global__ __launch_bounds__(256) void k_wt(const float* __restrict__ conv_w,
                                            unsigned short* __restrict__ wt) {
  int kk = blockIdx.x * 256 + threadIdx.x;  // 0..2303
  int k = blockIdx.y;                       // 0..511
  int j = kk >> 8, e = kk & 255;
  wt[(size_t)k * KK_ + kk] = f2bf(conv_w[(k * E_ + e) * KS_ + j]);
}

// ---------------- prep: U_w / final_w fp32 -> bf16 ----------------
__global__ __launch_bounds__(256) void k_cast(const float* __restrict__ U_w,
                                              const float* __restrict__ F_w,
                                              unsigned short* __restrict__ ubf,
                                              unsigned short* __restrict__ fbf) {
  int gid = blockIdx.x * 256 + threadIdx.x;
  const float* src = blockIdx.y ? F_w : U_w;
  unsigned short* dst = blockIdx.y ? fbf : ubf;
  size_t base = (size_t)gid * 8;
  float4 v0 = *(const float4*)(src + base);
  float4 v1 = *(const float4*)(src + base + 4);
  ushort4 o0, o1;
  o0.x = f2bf(v0.x); o0.y = f2bf(v0.y); o0.z = f2bf(v0.z); o0.w = f2bf(v0.w);
  o1.x = f2bf(v1.x); o1.y = f2bf(v1.y); o1.z = f2bf(v1.z); o1.w = f2bf(v1.w);
  *(ushort4*)(dst + base) = o0;
  *(ushort4*)(dst + base + 4) = o1;
}

// ---------------- conv1d as MFMA GEMM: feats[b,t,k] = relu(conv) bf16 ----------------
__global__ __launch_bounds__(256) void k_conv(const unsigned short* __restrict__ xpad,
                                              const unsigned short* __restrict__ wt,
                                              const float* __restrict__ conv_b,
                                              unsigned short* __restrict__ feats) {
  __shared__ short At[128 * 32];
  __shared__ short Bt[128 * 32];
  const int tid = threadIdx.x;
  const int w = tid >> 6, lane = tid & 63;
  const int q = lane >> 4, c = lane & 15;
  const int wi = w >> 1, wj = w & 1;
  const int b = blockIdx.z;
  const int t0 = blockIdx.y * 128;
  const int n0 = blockIdx.x * 128;

  f32x4 acc[4][4];
  f32x4 zero = {0.f, 0.f, 0.f, 0.f};
#pragma unroll
  for (int i = 0; i < 4; ++i)
#pragma unroll
    for (int j = 0; j < 4; ++j) acc[i][j] = zero;

  const unsigned short* xb = xpad + (size_t)b * TP_ * E_;

  for (int kkc = 0; kkc < KK_; kkc += 32) {
    __syncthreads();
    const int jconv = kkc >> 8;
    const int ebase = kkc & 255;
#pragma unroll
    for (int rnd = 0; rnd < 2; ++rnd) {
      int s = rnd * 256 + tid;          // chunk slot 0..511
      int r = s >> 2;
      int qq = ((s & 3) - (r >> 1)) & 3;
      int ldsoff = (w * 64 + rnd * 256) * 8;  // shorts
      gld_lds16(xb + (size_t)(t0 + r + jconv) * E_ + ebase + 8 * qq, (void*)(At + ldsoff));
      gld_lds16(wt + (size_t)(n0 + r) * KK_ + kkc + 8 * qq, (void*)(Bt + ldsoff));
    }
    __syncthreads();
    bf16x8 afr[4];
#pragma unroll
    for (int li = 0; li < 4; ++li) {
      int r = wi * 64 + li * 16 + c;
      afr[li] = *(const bf16x8*)(At + frag_off(r, q));
    }
#pragma unroll
    for (int ti = 0; ti < 4; ++ti) {
      int r = wj * 64 + ti * 16 + c;
      bf16x8 bfr = *(const bf16x8*)(Bt + frag_off(r, q));
#pragma unroll
      for (int li = 0; li < 4; ++li)
        acc[li][ti] = mfma_bf16(afr[li], bfr, acc[li][ti]);
    }
  }

  // epilogue: +bias, relu, bf16 store. C/D: row=(lane>>4)*4+rr, col=lane&15
#pragma unroll
  for (int ti = 0; ti < 4; ++ti) {
    int k = n0 + wj * 64 + ti * 16 + c;
    float bias = conv_b[k];
#pragma unroll
    for (int li = 0; li < 4; ++li) {
      int tb = t0 + wi * 64 + li * 16 + q * 4;
#pragma unroll
      for (int rr = 0; rr < 4; ++rr) {
        float v = acc[li][ti][rr] + bias;
        v = fmaxf(v, 0.f);
        feats[((size_t)(b * T_ + tb + rr)) * K_ + k] = f2bf(v);
      }
    }
  }
}

// ---------------- fused label-attention: S,V GEMMs + softmax-weighted reduce ----------------
__global__ __launch_bounds__(256) void k_attn(const unsigned short* __restrict__ feats,
                                              const unsigned short* __restrict__ ubf,
                                              const unsigned short* __restrict__ fbf,
                                              const float* __restrict__ final_b,
                                              float* __restrict__ out) {
  __shared__ short Ft[128 * 32];
  __shared__ short Ut[128 * 32];
  __shared__ short Wt[128 * 32];
  __shared__ float red[4 * 128];  // [wj*128+r]=num, [(2+wj)*128+r]=den
  const int tid = threadIdx.x;
  const int w = tid >> 6, lane = tid & 63;
  const int q = lane >> 4, c = lane & 15;
  const int wi = w >> 1, wj = w & 1;
  const int b = blockIdx.y;
  const int l0 = blockIdx.x * 128;

  const unsigned short* fb = feats + (size_t)b * T_ * K_;

  float num_acc[4][4], den_acc[4][4];
#pragma unroll
  for (int li = 0; li < 4; ++li)
#pragma unroll
    for (int rr = 0; rr < 4; ++rr) { num_acc[li][rr] = 0.f; den_acc[li][rr] = 0.f; }

  for (int t0 = 0; t0 < T_; t0 += 128) {
    f32x4 accS[4][4], accV[4][4];
    f32x4 zero = {0.f, 0.f, 0.f, 0.f};
#pragma unroll
    for (int i = 0; i < 4; ++i)
#pragma unroll
      for (int j = 0; j < 4; ++j) { accS[i][j] = zero; accV[i][j] = zero; }

    for (int kc = 0; kc < K_; kc += 32) {
      __syncthreads();
#pragma unroll
      for (int rnd = 0; rnd < 2; ++rnd) {
        int s = rnd * 256 + tid;
        int r = s >> 2;
        int qq = ((s & 3) - (r >> 1)) & 3;
        int ldsoff = (w * 64 + rnd * 256) * 8;
        gld_lds16(fb + (size_t)(t0 + r) * K_ + kc + 8 * qq, (void*)(Ft + ldsoff));
        gld_lds16(ubf + (size_t)(l0 + r) * K_ + kc + 8 * qq, (void*)(Ut + ldsoff));
        gld_lds16(fbf + (size_t)(l0 + r) * K_ + kc + 8 * qq, (void*)(Wt + ldsoff));
      }
      __syncthreads();
      bf16x8 au[4], aw[4];
#pragma unroll
      for (int li = 0; li < 4; ++li) {
        int r = wi * 64 + li * 16 + c;
        int off = frag_off(r, q);
        au[li] = *(const bf16x8*)(Ut + off);
        aw[li] = *(const bf16x8*)(Wt + off);
      }
#pragma unroll
      for (int ti = 0; ti < 4; ++ti) {
        int r = wj * 64 + ti * 16 + c;
        bf16x8 bfr = *(const bf16x8*)(Ft + frag_off(r, q));
#pragma unroll
        for (int li = 0; li < 4; ++li) {
          accS[li][ti] = mfma_bf16(au[li], bfr, accS[li][ti]);
          accV[li][ti] = mfma_bf16(aw[li], bfr, accV[li][ti]);
        }
      }
    }
    // softmax-weighted accumulation; scores are O(0.1) so exp() needs no max-shift.
    // num/den are additive per row -> cross-lane reduce deferred to the end.
#pragma unroll
    for (int li = 0; li < 4; ++li)
#pragma unroll
      for (int ti = 0; ti < 4; ++ti)
#pragma unroll
        for (int rr = 0; rr < 4; ++rr) {
          float p = __expf(accS[li][ti][rr]);
          den_acc[li][rr] += p;
          num_acc[li][rr] += p * accV[li][ti][rr];
        }
  }

  // 16-lane (t-column) butterfly reduce
#pragma unroll
  for (int li = 0; li < 4; ++li)
#pragma unroll
    for (int rr = 0; rr < 4; ++rr) {
      float n = num_acc[li][rr], d = den_acc[li][rr];
#pragma unroll
      for (int m = 1; m < 16; m <<= 1) {
        n += __shfl_xor(n, m, 64);
        d += __shfl_xor(d, m, 64);
      }
      num_acc[li][rr] = n; den_acc[li][rr] = d;
    }
  if (c == 0) {
#pragma unroll
    for (int li = 0; li < 4; ++li)
#pragma unroll
      for (int rr = 0; rr < 4; ++rr) {
        int r = wi * 64 + li * 16 + q * 4 + rr;
        red[wj * 128 + r] = num_acc[li][rr];
        red[(2 + wj) * 128 + r] = den_acc[li][rr];
      }
  }
  __syncthreads();
  if (tid < 128) {
    int l = l0 + tid;
    float n = red[tid] + red[128 + tid];
    float d = red[256 + tid] + red[384 + tid];
    out[(size_t)b * L_ + l] = n / d + final_b[l];
  }
}

// ---------------- BCE-with-logits mean ----------------
__global__ __launch_bounds__(256) void k_loss(const float* __restrict__ yhat,
                                              const float* __restrict__ target,
                                              float* __restrict__ loss) {
  int gid = blockIdx.x * 256 + threadIdx.x;
  float s = 0.f;
  for (int i = gid; i < B_ * L_; i += 64 * 256) {
    float y = yhat[i], t = target[i];
    s += fmaxf(y, 0.f) - y * t + log1pf(__expf(-fabsf(y)));
  }
#pragma unroll
  for (int m = 1; m < 64; m <<= 1) s += __shfl_xor(s, m, 64);
  if ((threadIdx.x & 63) == 0) atomicAdd(loss, s * (1.0f / (B_ * L_)));
}

extern "C" void kernel_launch(void* const* d_in, const int* in_sizes, int n_in,
                              void* d_out, int out_size, void* d_ws, size_t ws_size,
                              hipStream_t stream) {
  const int* ids = (const int*)d_in[0];
  const float* target = (const float*)d_in[3];
  const float* emb = (const float*)d_in[4];
  const float* conv_w = (const float*)d_in[5];
  const float* conv_b = (const float*)d_in[6];
  const float* U_w = (const float*)d_in[7];
  const float* F_w = (const float*)d_in[8];
  const float* final_b = (const float*)d_in[9];
  float* out = (float*)d_out;

  unsigned short* ws = (unsigned short*)d_ws;
  unsigned short* xpad = ws;                                // B*TP*E
  unsigned short* wt = xpad + (size_t)B_ * TP_ * E_;        // K*KK
  unsigned short* ubf = wt + (size_t)K_ * KK_;              // L*K
  unsigned short* fbf = ubf + (size_t)L_ * K_;              // L*K
  unsigned short* feats = fbf + (size_t)L_ * K_;            // B*T*K
  size_t need = ((size_t)B_ * TP_ * E_ + (size_t)K_ * KK_ +
                 2 * (size_t)L_ * K_ + (size_t)B_ * T_ * K_) * 2;
  if (ws_size < need) return;

  k_embed<<<dim3((B_ * TP_ * 64) / 256), 256, 0, stream>>>(ids, emb, xpad);
  k_wt<<<dim3(KK_ / 256, K_), 256, 0, stream>>>(conv_w, wt);
  k_cast<<<dim3((L_ * K_ / 8) / 256, 2), 256, 0, stream>>>(U_w, F_w, ubf, fbf);
  k_conv<<<dim3(K_ / 128, T_ / 128, B_), 256, 0, stream>>>(xpad, wt, conv_b, feats);
  k_attn<<<dim3(L_ / 128, B_), 256, 0, stream>>>(feats, ubf, fbf, final_b, out);
  hipMemsetAsync(out + B_ * L_, 0, sizeof(float), stream);
  k_loss<<<dim3(64), 256, 0, stream>>>(out, target, out + B_ * L_);
}